// Round 6
// baseline (38.704 us; speedup 1.0000x reference)
//
#include <hip/hip_runtime.h>

// Sobel-like 4-kernel depthwise edge detector + sigmoid>0.5 threshold.
// Output[p] = (|e0|+|e1|+|e2|+|e3| > 0) ? 1.0f : 0.0f, with zero padding.
//
// x: (32,3,512,512) f32 -> 96 independent 512x512 images.
// One wave owns a full 512-px row-strip, 8 output rows tall (10 input rows),
// processed through a rolling 3-row register window so loads/compute/stores
// interleave. Lane i owns px [i*4,i*4+4) (half A) and [256+i*4,...) (half B):
// every load/store is 64 lanes x 16 B fully contiguous. Halos via __shfl.
// Block swizzle: 1536 blocks = 8 XCDs x 192; each XCD gets 12 contiguous
// images so strip-halo rows stay in one XCD's L2.

#define IMG_H 512
#define IMG_W 512

typedef float f32x4 __attribute__((ext_vector_type(4)));

__device__ __forceinline__ void load_row(const float* __restrict__ base, int h,
                                         int wA, int wB, int lane,
                                         float (&A)[6], float (&B)[6]) {
    if (h >= 0 && h < IMG_H) {            // wave-uniform
        const float* rp = base + h * IMG_W;
        f32x4 a = *reinterpret_cast<const f32x4*>(rp + wA);
        f32x4 b = *reinterpret_cast<const f32x4*>(rp + wB);
        A[1] = a.x; A[2] = a.y; A[3] = a.z; A[4] = a.w;
        B[1] = b.x; B[2] = b.y; B[3] = b.z; B[4] = b.w;
        float a_l = __shfl_up(a.w, 1);    // lane-1's px i*4-1
        float a_r = __shfl_down(a.x, 1);  // lane+1's px i*4+4
        float b_l = __shfl_up(b.w, 1);
        float b_r = __shfl_down(b.x, 1);
        float seam_r = __shfl(b.x, 0);    // px 256
        float seam_l = __shfl(a.w, 63);   // px 255
        A[0] = (lane == 0)  ? 0.0f   : a_l;
        A[5] = (lane == 63) ? seam_r : a_r;
        B[0] = (lane == 0)  ? seam_l : b_l;
        B[5] = (lane == 63) ? 0.0f   : b_r;
    } else {
#pragma unroll
        for (int i = 0; i < 6; ++i) { A[i] = 0.0f; B[i] = 0.0f; }
    }
}

__device__ __forceinline__ void sobel4(const float (&T)[6], const float (&M)[6],
                                       const float (&Bt)[6], f32x4& o) {
#pragma unroll
    for (int j = 0; j < 4; ++j) {
        float t0 = T[j], t1 = T[j + 1], t2 = T[j + 2];
        float m0 = M[j],                m2 = M[j + 2];
        float b0 = Bt[j], b1 = Bt[j + 1], b2 = Bt[j + 2];
        // e0,e1 direct; e2,e3 via exact factorization:
        // k2 = (k1-k0)/2 + [[1,0,0],[0,0,0],[0,0,-1]]
        // k3 = -(k0+k1)/2 + [[0,0,-1],[0,0,0],[1,0,0]]
        float e0 = (t2 - t0) + 2.0f * (m2 - m0) + (b2 - b0);
        float e1 = (t0 + 2.0f * t1 + t2) - (b0 + 2.0f * b1 + b2);
        float e2 = 0.5f * (e1 - e0) + (t0 - b2);
        float e3 = -0.5f * (e0 + e1) + (b0 - t2);
        float s = fabsf(e0) + fabsf(e1) + fabsf(e2) + fabsf(e3);
        o[j] = (s > 0.0f) ? 1.0f : 0.0f;
    }
}

__global__ __launch_bounds__(256) void sobel_thresh_kernel(
    const float* __restrict__ x, float* __restrict__ out) {
    // XCD-aware bijective swizzle: 1536 blocks = 8 x 192.
    int bid  = blockIdx.x;
    int sbid = (bid & 7) * 192 + (bid >> 3);
    int t    = sbid * 256 + (int)threadIdx.x;
    int lane = t & 63;
    int wid  = t >> 6;        // 0..6143 : one wave per (img, 8-row group)
    int hg   = wid & 63;
    int img  = wid >> 6;
    int h0   = hg << 3;
    int wA   = lane << 2;
    int wB   = 256 + (lane << 2);

    const float* base = x + (size_t)img * (IMG_H * IMG_W);
    float* obase = out + (size_t)img * (IMG_H * IMG_W) + (size_t)h0 * IMG_W;

    // rolling 3-row window, statically rotated (fully unrolled)
    float WA[3][6], WB[3][6];
    load_row(base, h0 - 1, wA, wB, lane, WA[0], WB[0]);
    load_row(base, h0,     wA, wB, lane, WA[1], WB[1]);

#pragma unroll
    for (int i = 0; i < 8; ++i) {
        load_row(base, h0 + 1 + i, wA, wB, lane, WA[(i + 2) % 3], WB[(i + 2) % 3]);
        f32x4 oA, oB;
        sobel4(WA[i % 3], WA[(i + 1) % 3], WA[(i + 2) % 3], oA);
        sobel4(WB[i % 3], WB[(i + 1) % 3], WB[(i + 2) % 3], oB);
        float* op = obase + i * IMG_W;
        __builtin_nontemporal_store(oA, reinterpret_cast<f32x4*>(op + wA));
        __builtin_nontemporal_store(oB, reinterpret_cast<f32x4*>(op + wB));
    }
}

extern "C" void kernel_launch(void* const* d_in, const int* in_sizes, int n_in,
                              void* d_out, int out_size, void* d_ws, size_t ws_size,
                              hipStream_t stream) {
    const float* x = (const float*)d_in[0];
    float* out = (float*)d_out;
    // 96 imgs * 64 row-groups = 6144 waves = 1536 blocks
    int grid = 1536;
    int block = 256;
    sobel_thresh_kernel<<<grid, block, 0, stream>>>(x, out);
}